// Round 5
// baseline (415.496 us; speedup 1.0000x reference)
//
#include <hip/hip_runtime.h>
#include <cstdint>
#include <cstddef>

#define SEQ 2048
#define DIMM 2048
#define NHEADS 8
#define HDIM 256
#define BATCH 2
#define NROWS 4096      // BATCH*SEQ
#define EDIM 2048       // NHEADS*HDIM
#define NQKV 6144       // 3*EDIM
#define SCALE 0.0625f   // 1/sqrt(256)
#define LOG2E 1.44269504f

typedef __attribute__((ext_vector_type(8))) short bf16x8;   // 8 bf16 in 4 VGPRs
typedef __attribute__((ext_vector_type(4))) float f32x4;
typedef __attribute__((ext_vector_type(16))) float f32x16;
typedef unsigned short u16;
typedef unsigned int u32;

__device__ __forceinline__ u16 f2bf(float f) {
  union { float f; u32 u; } v; v.f = f;
  u32 r = (v.u + 0x7fffu + ((v.u >> 16) & 1u)) >> 16;   // RNE
  return (u16)r;
}
__device__ __forceinline__ float bf2f(u16 b) {
  union { u32 u; float f; } v; v.u = ((u32)b) << 16;
  return v.f;
}
// async global->LDS, 16B per lane. LDS layout must be lane-linear (wave base + lane*16).
__device__ __forceinline__ void gload16(const void* g, void* l) {
  __builtin_amdgcn_global_load_lds(
      (__attribute__((address_space(1))) void*)(void*)g,
      (__attribute__((address_space(3))) void*)l, 16, 0, 0);
}

// ---------------- cast + k-packet transpose ----------------
// xbP[k/8][m] and WcatP[k/8][n]: 16B packets of 8 bf16 along k, row-major within a
// k-slot panel. This makes BOTH the GEMM's global_load_lds source AND the 32x32x16
// MFMA frag ds_read contiguous (lane i -> base + i*16) — the one LDS pattern measured
// conflict-free on this HW (gload-write pattern). Replaces the XOR-swizzle approach
// whose reads measured ~4 extra cyc each (12.6M conflicts/dispatch, r4 counters).
// blocks [0,2048): x tiles; [2048,5120): Wq/Wk/Wv tiles; [5120,6144): Wo linear cast.
__global__ void __launch_bounds__(256) cast_pack(const float* __restrict__ x,
                                                 const float* __restrict__ wq,
                                                 const float* __restrict__ wk,
                                                 const float* __restrict__ wv,
                                                 const float4* __restrict__ wo,
                                                 uint4* __restrict__ xbp,
                                                 uint4* __restrict__ wcatp,
                                                 ushort4* __restrict__ wob) {
  const int bid = blockIdx.x;
  const int tid = threadIdx.x;
  if (bid < 5120) {
    __shared__ u16 t[64][72];          // 64x64 bf16 tile, row stride 144B (16B-aligned)
    const bool isx = (bid < 2048);
    const int tt = isx ? bid : bid - 2048;
    const int r0 = (tt >> 5) << 6;     // output row (m or n) tile base
    const int c0 = (tt & 31) << 6;     // k tile base
    const float* src;
    int srow;
    if (isx) { src = x; srow = r0; }
    else {
      const int sel = r0 >> 11;        // 0..2 -> Wq/Wk/Wv
      src = (sel == 0) ? wq : ((sel == 1) ? wk : wv);
      srow = r0 & 2047;
    }
    // read 64x64 fp32 (coalesced rows), cast, store to LDS
#pragma unroll
    for (int i = 0; i < 4; ++i) {
      const int idx = i * 256 + tid;           // 0..1023
      const int r = idx >> 4, c4 = idx & 15;
      const float4 v = *(const float4*)(src + (long)(srow + r) * 2048 + c0 + c4 * 4);
      ushort4 o;
      o.x = f2bf(v.x); o.y = f2bf(v.y); o.z = f2bf(v.z); o.w = f2bf(v.w);
      *(ushort4*)&t[r][c4 * 4] = o;
    }
    __syncthreads();
    // write packets: packet (u_global = c0/8 + u) x row (r0 + m); contiguous 1KB/wave
    uint4* dst = isx ? xbp : wcatp;
    const long R = isx ? 4096L : 6144L;
#pragma unroll
    for (int i = 0; i < 2; ++i) {
      const int p = i * 256 + tid;             // 0..511
      const int u = p >> 6, m = p & 63;
      const uint4 pk = *(const uint4*)&t[m][u * 8];
      dst[(long)((c0 >> 3) + u) * R + r0 + m] = pk;
    }
  } else {
    // Wo: plain row-major cast (gemm2 keeps the row-major kernel)
    const int b2 = bid - 5120;
#pragma unroll
    for (int i = 0; i < 4; ++i) {
      const long o = (long)b2 * 1024 + i * 256 + tid;
      const float4 v = wo[o];
      ushort4 ov;
      ov.x = f2bf(v.x); ov.y = f2bf(v.y); ov.z = f2bf(v.z); ov.w = f2bf(v.w);
      wob[o] = ov;
    }
  }
}

// ---------------- GEMM (128x128 row-major, kept for the output projection) -----------
template<int BF16OUT>
__global__ void __launch_bounds__(256) gemm_bt(const u16* __restrict__ A,
                                               const u16* __restrict__ B,
                                               void* __restrict__ Cout,
                                               int N, int K) {
  __shared__ __align__(16) u16 As[128 * 64];
  __shared__ __align__(16) u16 Bs[128 * 64];
  const int tid = threadIdx.x;
  const int wave = tid >> 6, lane = tid & 63;
  const int l32 = lane & 31, half = lane >> 5;
  const long bm = (long)blockIdx.x * 128, bn = (long)blockIdx.y * 128;
  const int wm = (wave >> 1) * 64, wn = (wave & 1) * 64;
  f32x16 acc[2][2];
#pragma unroll
  for (int i = 0; i < 2; ++i)
#pragma unroll
    for (int j = 0; j < 2; ++j)
#pragma unroll
      for (int r = 0; r < 16; ++r) acc[i][j][r] = 0.f;

  for (int k0 = 0; k0 < K; k0 += 64) {
#pragma unroll
    for (int p = 0; p < 4; ++p) {
      const int o = p * 4096 + tid * 16;
      const int row = o >> 7;
      const int cg = ((o >> 4) & 7) ^ (row & 7);
      gload16(A + (bm + row) * (long)K + k0 + cg * 8, (char*)As + o);
      gload16(B + (bn + row) * (long)K + k0 + cg * 8, (char*)Bs + o);
    }
    __syncthreads();
#pragma unroll
    for (int ks = 0; ks < 4; ++ks) {
      bf16x8 af[2], bfr[2];
#pragma unroll
      for (int t = 0; t < 2; ++t) {
        const int ar = wm + t * 32 + l32;
        const int br = wn + t * 32 + l32;
        const int u = ks * 2 + half;
        af[t]  = *(const bf16x8*)(As + ar * 64 + ((u ^ (ar & 7)) * 8));
        bfr[t] = *(const bf16x8*)(Bs + br * 64 + ((u ^ (br & 7)) * 8));
      }
#pragma unroll
      for (int i = 0; i < 2; ++i)
#pragma unroll
        for (int j = 0; j < 2; ++j)
          acc[i][j] = __builtin_amdgcn_mfma_f32_32x32x16_bf16(af[i], bfr[j], acc[i][j], 0, 0, 0);
    }
    __syncthreads();
  }
#pragma unroll
  for (int i = 0; i < 2; ++i)
#pragma unroll
    for (int j = 0; j < 2; ++j)
#pragma unroll
      for (int r = 0; r < 16; ++r) {
        const long row = bm + wm + i * 32 + (r & 3) + 8 * (r >> 2) + 4 * half;
        const long col = bn + wn + j * 32 + l32;
        const float v = acc[i][j][r];
        if (BF16OUT) ((u16*)Cout)[row * N + col] = f2bf(v);
        else         ((float*)Cout)[row * N + col] = v;
      }
}

// ---------------- GEMM 256x256 8-phase on k-packet layout (QKV projection) -----------
// Same 8-phase/counted-vmcnt ledger as the r2 kernel (HW-passed); only the LDS layout
// changed: As/Bs = [buf][half][u:8][r:128] packets. Frag read = two contiguous 512B
// half-wave runs (canonical clean pattern); stage = contiguous 1KB/wave both sides.
#define PHASEP(BUF, QM, QN, STAGE_STMT, VMW)                                       \
  do {                                                                             \
    bf16x8 af[2][4], bfr[4];                                                       \
    const u16* Ah = As + (BUF) * 16384 + (QM) * 8192;                              \
    const u16* Bh = Bs + (BUF) * 16384 + (QN) * 8192;                              \
    _Pragma("unroll")                                                              \
    for (int mb = 0; mb < 2; ++mb) {                                               \
      const int r_ = wm * 64 + mb * 32 + l32;                                      \
      _Pragma("unroll")                                                            \
      for (int ks = 0; ks < 4; ++ks)                                               \
        af[mb][ks] = *(const bf16x8*)(Ah + (ks * 2 + kh) * 1024 + r_ * 8);         \
    }                                                                              \
    {                                                                              \
      const int br_ = wn * 32 + l32;                                               \
      _Pragma("unroll")                                                            \
      for (int ks = 0; ks < 4; ++ks)                                               \
        bfr[ks] = *(const bf16x8*)(Bh + (ks * 2 + kh) * 1024 + br_ * 8);           \
    }                                                                              \
    STAGE_STMT;                                                                    \
    __builtin_amdgcn_s_barrier();                                                  \
    asm volatile("s_waitcnt lgkmcnt(0)" ::: "memory");                             \
    __builtin_amdgcn_sched_barrier(0);                                             \
    __builtin_amdgcn_s_setprio(1);                                                 \
    _Pragma("unroll")                                                              \
    for (int mb = 0; mb < 2; ++mb)                                                 \
      _Pragma("unroll")                                                            \
      for (int ks = 0; ks < 4; ++ks)                                               \
        acc[QM][QN][mb] = __builtin_amdgcn_mfma_f32_32x32x16_bf16(                 \
            af[mb][ks], bfr[ks], acc[QM][QN][mb], 0, 0, 0);                        \
    __builtin_amdgcn_s_setprio(0);                                                 \
    if ((VMW) >= 0) {                                                              \
      if ((VMW) == 0) asm volatile("s_waitcnt vmcnt(0)" ::: "memory");             \
      else            asm volatile("s_waitcnt vmcnt(4)" ::: "memory");             \
    }                                                                              \
    __builtin_amdgcn_s_barrier();                                                  \
    __builtin_amdgcn_sched_barrier(0);                                             \
  } while (0)

__global__ void __launch_bounds__(512, 2) gemm_pk256(const uint4* __restrict__ AP,
                                                     const uint4* __restrict__ BP,
                                                     u16* __restrict__ Cout,
                                                     int AR, int BR, int mtiles,
                                                     int N, int K) {
  __shared__ __align__(16) u16 As[2 * 2 * 8 * 128 * 8];   // 64 KiB
  __shared__ __align__(16) u16 Bs[2 * 2 * 8 * 128 * 8];   // 64 KiB
  const int tid = threadIdx.x;
  const int lane = tid & 63;
  const int wave = tid >> 6;
  const int l32 = lane & 31, kh = lane >> 5;
  const int wm = wave >> 2, wn = wave & 3;
  const int cpx = gridDim.x >> 3;
  const int swz = ((int)blockIdx.x & 7) * cpx + ((int)blockIdx.x >> 3);
  const long bm = (long)(swz % mtiles) * 256;
  const long bn = (long)(swz / mtiles) * 256;
  const int NT = K >> 6;          // 64-wide K tiles (even)
  const int NIT = NT >> 1;

  f32x16 acc[2][2][2];
#pragma unroll
  for (int a = 0; a < 2; ++a)
#pragma unroll
    for (int b = 0; b < 2; ++b)
#pragma unroll
      for (int c = 0; c < 2; ++c)
#pragma unroll
        for (int r = 0; r < 16; ++r) acc[a][b][c][r] = 0.f;

  // stage one 16 KiB half-tile: LDS o=tid*16 -> (u=o>>11, r=(o>>4)&127);
  // source packet (t*8+u, base + h*128 + r) -> contiguous 1KB per wave.
  auto stA = [&](int buf, int t, int h) {
#pragma unroll
    for (int p = 0; p < 2; ++p) {
      const int o = p * 8192 + tid * 16;
      const int u = o >> 11, r = (o >> 4) & 127;
      gload16(AP + (long)(t * 8 + u) * AR + bm + h * 128 + r,
              (char*)As + buf * 32768 + h * 16384 + o);
    }
  };
  auto stB = [&](int buf, int t, int h) {
#pragma unroll
    for (int p = 0; p < 2; ++p) {
      const int o = p * 8192 + tid * 16;
      const int u = o >> 11, r = (o >> 4) & 127;
      gload16(BP + (long)(t * 8 + u) * BR + bn + h * 128 + r,
              (char*)Bs + buf * 32768 + h * 16384 + o);
    }
  };

  // prologue: tile0 full + tile1 {A-h0, B-h1}; leave tile1's 4 loads in flight
  stA(0, 0, 0); stA(0, 0, 1); stB(0, 0, 0); stB(0, 0, 1);
  stA(1, 1, 0); stB(1, 1, 1);
  asm volatile("s_waitcnt vmcnt(4)" ::: "memory");
  __builtin_amdgcn_s_barrier();
  __builtin_amdgcn_sched_barrier(0);

  for (int i = 0; i < NIT; ++i) {
    const int t1 = 2 * i + 1;
    const bool last = (i == NIT - 1);
    PHASEP(0, 0, 0, { stA(1, t1, 1); }, -1);
    PHASEP(0, 0, 1, { stB(1, t1, 0); }, -1);
    PHASEP(0, 1, 1, { if (!last) stA(0, t1 + 1, 0); }, -1);
    PHASEP(0, 1, 0, { if (!last) stB(0, t1 + 1, 1); }, last ? 0 : 4);
    PHASEP(1, 0, 0, { if (!last) stA(0, t1 + 1, 1); }, -1);
    PHASEP(1, 0, 1, { if (!last) stB(0, t1 + 1, 0); }, -1);
    PHASEP(1, 1, 1, { if (!last) stA(1, t1 + 2, 0); }, -1);
    PHASEP(1, 1, 0, { if (!last) stB(1, t1 + 2, 1); }, last ? -1 : 4);
  }

#pragma unroll
  for (int qm = 0; qm < 2; ++qm)
#pragma unroll
    for (int qn = 0; qn < 2; ++qn)
#pragma unroll
      for (int mb = 0; mb < 2; ++mb)
#pragma unroll
        for (int r = 0; r < 16; ++r) {
          const long row = bm + qm * 128 + wm * 64 + mb * 32 + (r & 3) + 8 * (r >> 2) + 4 * kh;
          const long col = bn + qn * 128 + wn * 32 + l32;
          Cout[row * N + col] = f2bf(acc[qm][qn][mb][r]);
        }
}

// ---------------- fused RMSnorm+RoPE (q/k) + V transpose, one launch ----------------
__global__ void __launch_bounds__(256) norm_rope_tv(u16* __restrict__ qkv,
                                                    const int* __restrict__ pos_ids,
                                                    const float* __restrict__ qw,
                                                    const float* __restrict__ kw,
                                                    u16* __restrict__ vt) {
  __shared__ u16 tile[64][73];
  if (blockIdx.x < 16384) {
    const int job = blockIdx.x * 4 + (threadIdx.x >> 6);
    const int lane = threadIdx.x & 63;
    const int which = job >> 15;       // 0 = q, 1 = k
    const int j2 = job & 32767;
    const int r = j2 >> 3;             // row 0..4095 (b*S+s)
    const int h = j2 & 7;
    const int s = r & (SEQ - 1);
    const int pos = pos_ids[s];
    const float* w = which ? kw : qw;
    u16* p = qkv + (long)r * NQKV + which * EDIM + h * HDIM;

    float x0 = bf2f(p[lane]);
    float x1 = bf2f(p[lane + 64]);
    float x2 = bf2f(p[lane + 128]);
    float x3 = bf2f(p[lane + 192]);
    float ss = x0 * x0 + x1 * x1 + x2 * x2 + x3 * x3;
#pragma unroll
    for (int off = 1; off < 64; off <<= 1) ss += __shfl_xor(ss, off);
    const float rinv = rsqrtf(ss * (1.0f / HDIM) + 1e-6f);
    x0 *= rinv * w[lane];       x1 *= rinv * w[lane + 64];
    x2 *= rinv * w[lane + 128]; x3 *= rinv * w[lane + 192];
    const float L2TEN4 = 13.287712379549449f;  // log2(10000)
    const float f0 = exp2f(-(2.0f * lane / HDIM) * L2TEN4);
    const float f1 = exp2f(-(2.0f * (lane + 64) / HDIM) * L2TEN4);
    const float a0 = pos * f0, a1 = pos * f1;
    float s0, c0, s1, c1;
    __sincosf(a0, &s0, &c0);
    __sincosf(a1, &s1, &c1);
    p[lane]       = f2bf(x0 * c0 - x2 * s0);
    p[lane + 64]  = f2bf(x1 * c1 - x3 * s1);
    p[lane + 128] = f2bf(x2 * c0 + x0 * s0);
    p[lane + 192] = f2bf(x3 * c1 + x1 * s1);
  } else {
    const int t = blockIdx.x - 16384;
    const int tid = threadIdx.x;
    const int st = (t & 31) * 64;
    const int dt = ((t >> 5) & 3) * 64;
    const int bh = t >> 7;
    const int b = bh >> 3, h = bh & 7;
    const u16* src = qkv + (long)(b * SEQ + st) * NQKV + 2 * EDIM + h * HDIM + dt;
#pragma unroll
    for (int p = 0; p < 2; ++p) {
      const int idx = p * 2048 + tid * 8;
      const int sr = idx >> 6, dc = idx & 63;
      const uint4 v = *(const uint4*)(src + (long)sr * NQKV + dc);
      const u16* pv = (const u16*)&v;
#pragma unroll
      for (int e = 0; e < 8; ++e) tile[sr][dc + e] = pv[e];
    }
    __syncthreads();
    u16* dst = vt + ((long)bh * HDIM + dt) * SEQ + st;
#pragma unroll
    for (int p = 0; p < 2; ++p) {
      const int idx = p * 2048 + tid * 8;
      const int dr = idx >> 6, sc = idx & 63;
      u16 tmp[8];
#pragma unroll
      for (int e = 0; e < 8; ++e) tmp[e] = tile[sc + e][dr];
      *(uint4*)(dst + (long)dr * SEQ + sc) = *(const uint4*)tmp;
    }
  }
}

// ---------------- flash attention v3 (r4 config): 2-barrier loop + T5 setprio --------
__global__ void __launch_bounds__(256) flash_attn(const u16* __restrict__ qkv,
                                                  const u16* __restrict__ vt,
                                                  u16* __restrict__ opart,
                                                  float* __restrict__ lpart,
                                                  u16* __restrict__ ob) {
  const int bh = blockIdx.x, b = bh >> 3, h = bh & 7;
  const int qt = 31 - (int)blockIdx.y;
  const int kc = blockIdx.z;
  if (kc && qt < 16) return;
  const int kt0 = kc * 16;
  const int kt_end = (qt < kt0 + 15) ? qt : (kt0 + 15);

  __shared__ __align__(16) u16 Ks[64 * 256];
  __shared__ __align__(16) u16 Vs[256 * 64];
  __shared__ __align__(16) u16 Pb[4 * 16 * 64];
  const int tid = threadIdx.x;
  const int wave = tid >> 6, lane = tid & 63;
  const int quad = lane >> 4, l16 = lane & 15;
  const long qbase = (long)(b * SEQ + qt * 64) * NQKV + h * HDIM;
  const long kbase = (long)(b * SEQ) * NQKV + EDIM + h * HDIM;
  const long vbase = (long)bh * HDIM * SEQ;

#pragma unroll
  for (int p = 0; p < 8; ++p) {
    const int o = p * 4096 + tid * 16;
    const int row = o >> 9;
    const int cg = ((o >> 4) & 31) ^ (row & 7);
    gload16(qkv + qbase + (long)row * NQKV + cg * 8, (char*)Ks + o);
  }
  __syncthreads();
  bf16x8 qf[8];
  {
    const int qr = wave * 16 + l16;
#pragma unroll
    for (int ks = 0; ks < 8; ++ks) {
      const int u = ks * 4 + quad;
      qf[ks] = *(const bf16x8*)(Ks + qr * 256 + (u ^ (qr & 7)) * 8);
    }
  }
  __syncthreads();

#pragma unroll
  for (int p = 0; p < 8; ++p) {
    const int o = p * 4096 + tid * 16;
    const int row = o >> 9;
    const int cg = ((o >> 4) & 31) ^ (row & 7);
    gload16(qkv + kbase + (long)(kt0 * 64 + row) * NQKV + cg * 8, (char*)Ks + o);
  }

  const f32x4 fz = {0.f, 0.f, 0.f, 0.f};
  f32x4 O[16];
#pragma unroll
  for (int t = 0; t < 16; ++t) O[t] = fz;
  float lacc[4] = {0.f, 0.f, 0.f, 0.f};
  const float C1 = SCALE * LOG2E;
  const float C2 = 16.0f * LOG2E;

  for (int kt = kt0; kt <= kt_end; ++kt) {
    __syncthreads();
#pragma unroll
    for (int p = 0; p < 8; ++p) {
      const int o = p * 4096 + tid * 16;
      const int row = o >> 7;
      const int cg = ((o >> 4) & 7) ^ (row & 7);
      gload16(vt + vbase + (long)row * SEQ + kt * 64 + cg * 8, (char*)Vs + o);
    }
    f32x4 S[4];
#pragma unroll
    for (int nt = 0; nt < 4; ++nt) S[nt] = fz;
    __builtin_amdgcn_s_setprio(1);
#pragma unroll
    for (int nt = 0; nt < 4; ++nt) {
      const int kr = nt * 16 + l16;
#pragma unroll
      for (int ks = 0; ks < 8; ++ks) {
        const int u = ks * 4 + quad;
        const bf16x8 kf = *(const bf16x8*)(Ks + kr * 256 + (u ^ (kr & 7)) * 8);
        S[nt] = __builtin_amdgcn_mfma_f32_16x16x32_bf16(qf[ks], kf, S[nt], 0, 0, 0);
      }
    }
    __builtin_amdgcn_s_setprio(0);
    u16* Pw = Pb + wave * (16 * 64);
    if (kt == qt) {
      const int qg0 = qt * 64 + wave * 16 + quad * 4;
      const int kg0 = kt * 64 + l16;
#pragma unroll
      for (int nt = 0; nt < 4; ++nt) {
        const int kg = kg0 + nt * 16;
#pragma unroll
        for (int r = 0; r < 4; ++r) {
          float p = exp2f(S[nt][r] * C1 - C2);
          p = (kg <= qg0 + r) ? p : 0.f;
          lacc[r] += p;
          const int qrow = quad * 4 + r;
          const int col = nt * 16 + l16;
          Pw[qrow * 64 + (((col >> 3) ^ (qrow & 7)) * 8) + (col & 7)] = f2bf(p);
        }
      }
    } else {
#pragma unroll
      for (int nt = 0; nt < 4; ++nt) {
#pragma unroll
        for (int r = 0; r < 4; ++r) {
          const float p = exp2f(S[nt][r] * C1 - C2);
          lacc[r] += p;
          const int qrow = quad * 4 + r;
          const int col = nt * 16 + l16;
          Pw[qrow * 64 + (((col >> 3) ^ (qrow & 7)) * 8) + (col & 7)] = f2bf(p);
        }
      }
    }
    __syncthreads();
    if (kt < kt_end) {
#pragma unroll
      for (int p = 0; p < 8; ++p) {
        const int o = p * 4096 + tid * 16;
        const int row = o >> 9;
        const int cg = ((o >> 4) & 31) ^ (row & 7);
        gload16(qkv + kbase + (long)((kt + 1) * 64 + row) * NQKV + cg * 8, (char*)Ks + o);
      }
    }
    bf16x8 pf[2];
#pragma unroll
    for (int ks = 0; ks < 2; ++ks) {
      const int u = ks * 4 + quad;
      pf[ks] = *(const bf16x8*)(Pw + l16 * 64 + (u ^ (l16 & 7)) * 8);
    }
    __builtin_amdgcn_s_setprio(1);
#pragma unroll
    for (int nt = 0; nt < 16; ++nt) {
      const int vr = nt * 16 + l16;
#pragma unroll
      for (int ks = 0; ks < 2; ++ks) {
        const int u = ks * 4 + quad;
        const bf16x8 vf = *(const bf16x8*)(Vs + vr * 64 + (u ^ (vr & 7)) * 8);
        O[nt] = __builtin_amdgcn_mfma_f32_16x16x32_bf16(pf[ks], vf, O[nt], 0, 0, 0);
      }
    }
    __builtin_amdgcn_s_setprio(0);
  }
#pragma unroll
  for (int off = 1; off < 16; off <<= 1)
#pragma unroll
    for (int r = 0; r < 4; ++r) lacc[r] += __shfl_xor(lacc[r], off);

  if (qt < 16) {
    const float rv[4] = {1.0f / lacc[0], 1.0f / lacc[1], 1.0f / lacc[2], 1.0f / lacc[3]};
#pragma unroll
    for (int nt = 0; nt < 16; ++nt) {
      const int col = nt * 16 + l16;
#pragma unroll
      for (int r = 0; r < 4; ++r) {
        const int qrow = wave * 16 + quad * 4 + r;
        ob[((long)(b * SEQ + qt * 64 + qrow)) * EDIM + h * HDIM + col] =
            f2bf(O[nt][r] * rv[r]);
      }
    }
  } else {
    const long pbase = ((long)(bh * 32 + qt) * 2 + kc) * (64 * 256);
#pragma unroll
    for (int nt = 0; nt < 16; ++nt) {
      const int col = nt * 16 + l16;
#pragma unroll
      for (int r = 0; r < 4; ++r) {
        const int qrow = wave * 16 + quad * 4 + r;
        opart[pbase + (long)qrow * 256 + col] = f2bf(O[nt][r]);
      }
    }
    if (l16 == 0) {
      const long lbase = ((long)(bh * 32 + qt) * 2 + kc) * 64;
#pragma unroll
      for (int r = 0; r < 4; ++r)
        lpart[lbase + wave * 16 + quad * 4 + r] = lacc[r];
    }
  }
}

// ---------------- combine split-K partials (qt>=16 only) ----------------
__global__ void __launch_bounds__(256) fa_combine(const u16* __restrict__ opart,
                                                  const float* __restrict__ lpart,
                                                  u16* __restrict__ ob) {
  const int bh = blockIdx.x, qt = 16 + blockIdx.y;
  const int b = bh >> 3, h = bh & 7;
  const long p0 = ((long)(bh * 32 + qt) * 2) * (64 * 256);
  const long l0 = ((long)(bh * 32 + qt) * 2) * 64;
  __shared__ float rl[64];
  if (threadIdx.x < 64) {
    const float l = lpart[l0 + threadIdx.x] + lpart[l0 + 64 + threadIdx.x];
    rl[threadIdx.x] = 1.0f / l;
  }
  __syncthreads();
#pragma unroll
  for (int i = 0; i < 8; ++i) {
    const int e = i * 2048 + threadIdx.x * 8;
    const int row = e >> 8, d = e & 255;
    const u16* a = opart + p0 + e;
    const u16* c = a + 64 * 256;
    float v[8];
#pragma unroll
    for (int j = 0; j < 8; ++j) v[j] = bf2f(a[j]) + bf2f(c[j]);
    const float inv = rl[row];
    u16 o[8];
#pragma unroll
    for (int j = 0; j < 8; ++j) o[j] = f2bf(v[j] * inv);
    *(uint4*)(ob + ((long)(b * SEQ + qt * 64 + row)) * EDIM + h * HDIM + d) =
        *(const uint4*)o;
  }
}

// ---------------- launch ----------------
extern "C" void kernel_launch(void* const* d_in, const int* in_sizes, int n_in,
                              void* d_out, int out_size, void* d_ws, size_t ws_size,
                              hipStream_t stream) {
  const float* x  = (const float*)d_in[0];
  const int* pos  = (const int*)d_in[1];
  const float* Wq = (const float*)d_in[2];
  const float* Wk = (const float*)d_in[3];
  const float* Wv = (const float*)d_in[4];
  const float* Wo = (const float*)d_in[5];
  const float* qw = (const float*)d_in[6];
  const float* kw = (const float*)d_in[7];

  char* ws = (char*)d_ws;
  uint4* xbP   = (uint4*)(ws);               // 16 MiB  x packets [256][4096]  [dead after GEMM1]
  uint4* WcatP = (uint4*)(ws + 16777216L);   // 24 MiB  W packets [256][6144]  [dead after GEMM1]
  u16* Wob  = (u16*)(ws + 41943040L);        //  8 MiB  Wo bf16 (row-major)
  u16* QKVb = (u16*)(ws + 50331648L);        // 48 MiB  qkv bf16 (4096x6144)
  u16* Vt   = (u16*)(ws + 100663296L);       // 16 MiB  V^T bf16 (16x256x2048)
  u16* Ob   = (u16*)(ws + 117440512L);       // 16 MiB  attn out bf16 (4096x2048)
  u16*   Opart = (u16*)(ws);                 // 32 MiB  overlay (dead xbP/WcatP region)
  float* Lpart = (float*)(ws + 33554432L);   // 256 KiB

  cast_pack<<<6144, 256, 0, stream>>>(x, Wq, Wk, Wv, (const float4*)Wo,
                                      xbP, WcatP, (ushort4*)Wob);

  // QKV projection: 256^2 8-phase on packet layout. grid = 16*24 = 384
  gemm_pk256<<<dim3(384), 512, 0, stream>>>(xbP, WcatP, QKVb, 4096, 6144, 16, NQKV, DIMM);
  norm_rope_tv<<<18432, 256, 0, stream>>>(QKVb, pos, qw, kw, Vt);
  flash_attn<<<dim3(16, 32, 2), 256, 0, stream>>>(QKVb, Vt, Opart, Lpart, Ob);
  fa_combine<<<dim3(16, 16), 256, 0, stream>>>(Opart, Lpart, Ob);
  gemm_bt<0><<<dim3(32, 16), 256, 0, stream>>>(Ob, Wob, d_out, EDIM, DIMM);
}

// Round 6
// 382.252 us; speedup vs baseline: 1.0870x; 1.0870x over previous
//
#include <hip/hip_runtime.h>
#include <cstdint>
#include <cstddef>

#define SEQ 2048
#define DIMM 2048
#define NHEADS 8
#define HDIM 256
#define BATCH 2
#define NROWS 4096      // BATCH*SEQ
#define EDIM 2048       // NHEADS*HDIM
#define NQKV 6144       // 3*EDIM
#define SCALE 0.0625f   // 1/sqrt(256)
#define LOG2E 1.44269504f

typedef __attribute__((ext_vector_type(8))) short bf16x8;   // 8 bf16 in 4 VGPRs
typedef __attribute__((ext_vector_type(4))) float f32x4;
typedef __attribute__((ext_vector_type(16))) float f32x16;
typedef unsigned short u16;
typedef unsigned int u32;

__device__ __forceinline__ u16 f2bf(float f) {
  union { float f; u32 u; } v; v.f = f;
  u32 r = (v.u + 0x7fffu + ((v.u >> 16) & 1u)) >> 16;   // RNE
  return (u16)r;
}
__device__ __forceinline__ float bf2f(u16 b) {
  union { u32 u; float f; } v; v.u = ((u32)b) << 16;
  return v.f;
}
// async global->LDS, 16B per lane. LDS layout must be lane-linear (wave base + lane*16).
__device__ __forceinline__ void gload16(const void* g, void* l) {
  __builtin_amdgcn_global_load_lds(
      (__attribute__((address_space(1))) void*)(void*)g,
      (__attribute__((address_space(3))) void*)l, 16, 0, 0);
}

// ---------------- cast + k-packet transpose (HW-verified r5: passed, 0 conflicts) -----
// xbP[k/8][m], WcatP[k/8][n]: 16B packets of 8 bf16 along k. Makes the GEMM's
// global_load_lds source AND the MFMA frag ds_read contiguous (lane i -> base+i*16),
// the canonical conflict-free LDS pattern (measured 0 conflicts in r5's gemm_pk256).
// blocks [0,2048): x tiles; [2048,5120): Wq/Wk/Wv tiles; [5120,6144): Wo linear cast.
__global__ void __launch_bounds__(256) cast_pack(const float* __restrict__ x,
                                                 const float* __restrict__ wq,
                                                 const float* __restrict__ wk,
                                                 const float* __restrict__ wv,
                                                 const float4* __restrict__ wo,
                                                 uint4* __restrict__ xbp,
                                                 uint4* __restrict__ wcatp,
                                                 ushort4* __restrict__ wob) {
  const int bid = blockIdx.x;
  const int tid = threadIdx.x;
  if (bid < 5120) {
    __shared__ u16 t[64][72];          // 64x64 bf16 tile, row stride 144B (16B-aligned)
    const bool isx = (bid < 2048);
    const int tt = isx ? bid : bid - 2048;
    const int r0 = (tt >> 5) << 6;     // output row (m or n) tile base
    const int c0 = (tt & 31) << 6;     // k tile base
    const float* src;
    int srow;
    if (isx) { src = x; srow = r0; }
    else {
      const int sel = r0 >> 11;        // 0..2 -> Wq/Wk/Wv
      src = (sel == 0) ? wq : ((sel == 1) ? wk : wv);
      srow = r0 & 2047;
    }
#pragma unroll
    for (int i = 0; i < 4; ++i) {
      const int idx = i * 256 + tid;           // 0..1023
      const int r = idx >> 4, c4 = idx & 15;
      const float4 v = *(const float4*)(src + (long)(srow + r) * 2048 + c0 + c4 * 4);
      ushort4 o;
      o.x = f2bf(v.x); o.y = f2bf(v.y); o.z = f2bf(v.z); o.w = f2bf(v.w);
      *(ushort4*)&t[r][c4 * 4] = o;
    }
    __syncthreads();
    uint4* dst = isx ? xbp : wcatp;
    const long R = isx ? 4096L : 6144L;
#pragma unroll
    for (int i = 0; i < 2; ++i) {
      const int p = i * 256 + tid;             // 0..511
      const int u = p >> 6, m = p & 63;
      const uint4 pk = *(const uint4*)&t[m][u * 8];
      dst[(long)((c0 >> 3) + u) * R + r0 + m] = pk;
    }
  } else {
    const int b2 = bid - 5120;
#pragma unroll
    for (int i = 0; i < 4; ++i) {
      const long o = (long)b2 * 1024 + i * 256 + tid;
      const float4 v = wo[o];
      ushort4 ov;
      ov.x = f2bf(v.x); ov.y = f2bf(v.y); ov.z = f2bf(v.z); ov.w = f2bf(v.w);
      wob[o] = ov;
    }
  }
}

// ---------------- GEMM 128x128 2-phase on k-packet layout (QKV projection) -----------
// A/B experiment vs r4: IDENTICAL loop/barrier structure to the 119us gemm_bt (38.5%
// MfmaUtil, 12.6M conflicts = ~4cyc/read surcharge on the LDS pipe); ONLY the LDS
// layout changes to packets [u:8][r:128] (r5-verified 0 conflicts, correct results).
// Theory: 2-phase at 3 blocks/CU is LDS-pipe-limited -> removing the conflict
// surcharge raises MfmaUtil toward ~48% and cuts dur to ~95us.
__global__ void __launch_bounds__(256) gemm_pk128(const uint4* __restrict__ AP,
                                                  const uint4* __restrict__ BP,
                                                  u16* __restrict__ Cout,
                                                  int AR, int BR, int N, int K) {
  __shared__ __align__(16) u16 As[8 * 128 * 8];   // 16 KB: packets [u:8][r:128]
  __shared__ __align__(16) u16 Bs[8 * 128 * 8];   // 16 KB
  const int tid = threadIdx.x;
  const int wave = tid >> 6, lane = tid & 63;
  const int l32 = lane & 31, kh = lane >> 5;
  const long bm = (long)blockIdx.x * 128, bn = (long)blockIdx.y * 128;
  const int wm = (wave >> 1) * 64, wn = (wave & 1) * 64;
  f32x16 acc[2][2];
#pragma unroll
  for (int i = 0; i < 2; ++i)
#pragma unroll
    for (int j = 0; j < 2; ++j)
#pragma unroll
      for (int r = 0; r < 16; ++r) acc[i][j][r] = 0.f;

  const int NT = K >> 6;
  for (int t = 0; t < NT; ++t) {
    // stage one 16KB tile per side: LDS o=tid*16 -> (u=o>>11, r=(o>>4)&127);
    // source packet (t*8+u, base + r): contiguous 1KB per wave both sides.
#pragma unroll
    for (int p = 0; p < 4; ++p) {
      const int o = p * 4096 + tid * 16;
      const int u = o >> 11, r = (o >> 4) & 127;
      gload16(AP + (long)(t * 8 + u) * AR + bm + r, (char*)As + o);
      gload16(BP + (long)(t * 8 + u) * BR + bn + r, (char*)Bs + o);
    }
    __syncthreads();
#pragma unroll
    for (int ks = 0; ks < 4; ++ks) {
      bf16x8 af[2], bfr[2];
      const int u = ks * 2 + kh;               // k-packet slot: k = ks*16 + kh*8 + j
#pragma unroll
      for (int t2 = 0; t2 < 2; ++t2) {
        const int ar = wm + t2 * 32 + l32;
        const int br = wn + t2 * 32 + l32;
        af[t2]  = *(const bf16x8*)(As + u * 1024 + ar * 8);   // contiguous, 0-conflict
        bfr[t2] = *(const bf16x8*)(Bs + u * 1024 + br * 8);
      }
#pragma unroll
      for (int i = 0; i < 2; ++i)
#pragma unroll
        for (int j = 0; j < 2; ++j)
          acc[i][j] = __builtin_amdgcn_mfma_f32_32x32x16_bf16(af[i], bfr[j], acc[i][j], 0, 0, 0);
    }
    __syncthreads();
  }
  // epilogue: 32x32 C/D layout col=lane&31, row=(reg&3)+8*(reg>>2)+4*kh
#pragma unroll
  for (int i = 0; i < 2; ++i)
#pragma unroll
    for (int j = 0; j < 2; ++j)
#pragma unroll
      for (int r = 0; r < 16; ++r) {
        const long row = bm + wm + i * 32 + (r & 3) + 8 * (r >> 2) + 4 * kh;
        const long col = bn + wn + j * 32 + l32;
        Cout[row * N + col] = f2bf(acc[i][j][r]);
      }
}

// ---------------- GEMM 128x128 row-major (kept for the output projection) ------------
template<int BF16OUT>
__global__ void __launch_bounds__(256) gemm_bt(const u16* __restrict__ A,
                                               const u16* __restrict__ B,
                                               void* __restrict__ Cout,
                                               int N, int K) {
  __shared__ __align__(16) u16 As[128 * 64];
  __shared__ __align__(16) u16 Bs[128 * 64];
  const int tid = threadIdx.x;
  const int wave = tid >> 6, lane = tid & 63;
  const int l32 = lane & 31, half = lane >> 5;
  const long bm = (long)blockIdx.x * 128, bn = (long)blockIdx.y * 128;
  const int wm = (wave >> 1) * 64, wn = (wave & 1) * 64;
  f32x16 acc[2][2];
#pragma unroll
  for (int i = 0; i < 2; ++i)
#pragma unroll
    for (int j = 0; j < 2; ++j)
#pragma unroll
      for (int r = 0; r < 16; ++r) acc[i][j][r] = 0.f;

  for (int k0 = 0; k0 < K; k0 += 64) {
#pragma unroll
    for (int p = 0; p < 4; ++p) {
      const int o = p * 4096 + tid * 16;
      const int row = o >> 7;
      const int cg = ((o >> 4) & 7) ^ (row & 7);
      gload16(A + (bm + row) * (long)K + k0 + cg * 8, (char*)As + o);
      gload16(B + (bn + row) * (long)K + k0 + cg * 8, (char*)Bs + o);
    }
    __syncthreads();
#pragma unroll
    for (int ks = 0; ks < 4; ++ks) {
      bf16x8 af[2], bfr[2];
#pragma unroll
      for (int t = 0; t < 2; ++t) {
        const int ar = wm + t * 32 + l32;
        const int br = wn + t * 32 + l32;
        const int u = ks * 2 + half;
        af[t]  = *(const bf16x8*)(As + ar * 64 + ((u ^ (ar & 7)) * 8));
        bfr[t] = *(const bf16x8*)(Bs + br * 64 + ((u ^ (br & 7)) * 8));
      }
#pragma unroll
      for (int i = 0; i < 2; ++i)
#pragma unroll
        for (int j = 0; j < 2; ++j)
          acc[i][j] = __builtin_amdgcn_mfma_f32_32x32x16_bf16(af[i], bfr[j], acc[i][j], 0, 0, 0);
    }
    __syncthreads();
  }
#pragma unroll
  for (int i = 0; i < 2; ++i)
#pragma unroll
    for (int j = 0; j < 2; ++j)
#pragma unroll
      for (int r = 0; r < 16; ++r) {
        const long row = bm + wm + i * 32 + (r & 3) + 8 * (r >> 2) + 4 * half;
        const long col = bn + wn + j * 32 + l32;
        const float v = acc[i][j][r];
        if (BF16OUT) ((u16*)Cout)[row * N + col] = f2bf(v);
        else         ((float*)Cout)[row * N + col] = v;
      }
}

// ---------------- fused RMSnorm+RoPE (q/k) + V transpose, one launch ----------------
__global__ void __launch_bounds__(256) norm_rope_tv(u16* __restrict__ qkv,
                                                    const int* __restrict__ pos_ids,
                                                    const float* __restrict__ qw,
                                                    const float* __restrict__ kw,
                                                    u16* __restrict__ vt) {
  __shared__ u16 tile[64][73];
  if (blockIdx.x < 16384) {
    const int job = blockIdx.x * 4 + (threadIdx.x >> 6);
    const int lane = threadIdx.x & 63;
    const int which = job >> 15;       // 0 = q, 1 = k
    const int j2 = job & 32767;
    const int r = j2 >> 3;             // row 0..4095 (b*S+s)
    const int h = j2 & 7;
    const int s = r & (SEQ - 1);
    const int pos = pos_ids[s];
    const float* w = which ? kw : qw;
    u16* p = qkv + (long)r * NQKV + which * EDIM + h * HDIM;

    float x0 = bf2f(p[lane]);
    float x1 = bf2f(p[lane + 64]);
    float x2 = bf2f(p[lane + 128]);
    float x3 = bf2f(p[lane + 192]);
    float ss = x0 * x0 + x1 * x1 + x2 * x2 + x3 * x3;
#pragma unroll
    for (int off = 1; off < 64; off <<= 1) ss += __shfl_xor(ss, off);
    const float rinv = rsqrtf(ss * (1.0f / HDIM) + 1e-6f);
    x0 *= rinv * w[lane];       x1 *= rinv * w[lane + 64];
    x2 *= rinv * w[lane + 128]; x3 *= rinv * w[lane + 192];
    const float L2TEN4 = 13.287712379549449f;  // log2(10000)
    const float f0 = exp2f(-(2.0f * lane / HDIM) * L2TEN4);
    const float f1 = exp2f(-(2.0f * (lane + 64) / HDIM) * L2TEN4);
    const float a0 = pos * f0, a1 = pos * f1;
    float s0, c0, s1, c1;
    __sincosf(a0, &s0, &c0);
    __sincosf(a1, &s1, &c1);
    p[lane]       = f2bf(x0 * c0 - x2 * s0);
    p[lane + 64]  = f2bf(x1 * c1 - x3 * s1);
    p[lane + 128] = f2bf(x2 * c0 + x0 * s0);
    p[lane + 192] = f2bf(x3 * c1 + x1 * s1);
  } else {
    const int t = blockIdx.x - 16384;
    const int tid = threadIdx.x;
    const int st = (t & 31) * 64;
    const int dt = ((t >> 5) & 3) * 64;
    const int bh = t >> 7;
    const int b = bh >> 3, h = bh & 7;
    const u16* src = qkv + (long)(b * SEQ + st) * NQKV + 2 * EDIM + h * HDIM + dt;
#pragma unroll
    for (int p = 0; p < 2; ++p) {
      const int idx = p * 2048 + tid * 8;
      const int sr = idx >> 6, dc = idx & 63;
      const uint4 v = *(const uint4*)(src + (long)sr * NQKV + dc);
      const u16* pv = (const u16*)&v;
#pragma unroll
      for (int e = 0; e < 8; ++e) tile[sr][dc + e] = pv[e];
    }
    __syncthreads();
    u16* dst = vt + ((long)bh * HDIM + dt) * SEQ + st;
#pragma unroll
    for (int p = 0; p < 2; ++p) {
      const int idx = p * 2048 + tid * 8;
      const int dr = idx >> 6, sc = idx & 63;
      u16 tmp[8];
#pragma unroll
      for (int e = 0; e < 8; ++e) tmp[e] = tile[sc + e][dr];
      *(uint4*)(dst + (long)dr * SEQ + sc) = *(const uint4*)tmp;
    }
  }
}

// ---------------- flash attention v3 (r4 config): 2-barrier loop + T5 setprio --------
__global__ void __launch_bounds__(256) flash_attn(const u16* __restrict__ qkv,
                                                  const u16* __restrict__ vt,
                                                  u16* __restrict__ opart,
                                                  float* __restrict__ lpart,
                                                  u16* __restrict__ ob) {
  const int bh = blockIdx.x, b = bh >> 3, h = bh & 7;
  const int qt = 31 - (int)blockIdx.y;
  const int kc = blockIdx.z;
  if (kc && qt < 16) return;
  const int kt0 = kc * 16;
  const int kt_end = (qt < kt0 + 15) ? qt : (kt0 + 15);

  __shared__ __align__(16) u16 Ks[64 * 256];
  __shared__ __align__(16) u16 Vs[256 * 64];
  __shared__ __align__(16) u16 Pb[4 * 16 * 64];
  const int tid = threadIdx.x;
  const int wave = tid >> 6, lane = tid & 63;
  const int quad = lane >> 4, l16 = lane & 15;
  const long qbase = (long)(b * SEQ + qt * 64) * NQKV + h * HDIM;
  const long kbase = (long)(b * SEQ) * NQKV + EDIM + h * HDIM;
  const long vbase = (long)bh * HDIM * SEQ;

#pragma unroll
  for (int p = 0; p < 8; ++p) {
    const int o = p * 4096 + tid * 16;
    const int row = o >> 9;
    const int cg = ((o >> 4) & 31) ^ (row & 7);
    gload16(qkv + qbase + (long)row * NQKV + cg * 8, (char*)Ks + o);
  }
  __syncthreads();
  bf16x8 qf[8];
  {
    const int qr = wave * 16 + l16;
#pragma unroll
    for (int ks = 0; ks < 8; ++ks) {
      const int u = ks * 4 + quad;
      qf[ks] = *(const bf16x8*)(Ks + qr * 256 + (u ^ (qr & 7)) * 8);
    }
  }
  __syncthreads();

#pragma unroll
  for (int p = 0; p < 8; ++p) {
    const int o = p * 4096 + tid * 16;
    const int row = o >> 9;
    const int cg = ((o >> 4) & 31) ^ (row & 7);
    gload16(qkv + kbase + (long)(kt0 * 64 + row) * NQKV + cg * 8, (char*)Ks + o);
  }

  const f32x4 fz = {0.f, 0.f, 0.f, 0.f};
  f32x4 O[16];
#pragma unroll
  for (int t = 0; t < 16; ++t) O[t] = fz;
  float lacc[4] = {0.f, 0.f, 0.f, 0.f};
  const float C1 = SCALE * LOG2E;
  const float C2 = 16.0f * LOG2E;

  for (int kt = kt0; kt <= kt_end; ++kt) {
    __syncthreads();
#pragma unroll
    for (int p = 0; p < 8; ++p) {
      const int o = p * 4096 + tid * 16;
      const int row = o >> 7;
      const int cg = ((o >> 4) & 7) ^ (row & 7);
      gload16(vt + vbase + (long)row * SEQ + kt * 64 + cg * 8, (char*)Vs + o);
    }
    f32x4 S[4];
#pragma unroll
    for (int nt = 0; nt < 4; ++nt) S[nt] = fz;
    __builtin_amdgcn_s_setprio(1);
#pragma unroll
    for (int nt = 0; nt < 4; ++nt) {
      const int kr = nt * 16 + l16;
#pragma unroll
      for (int ks = 0; ks < 8; ++ks) {
        const int u = ks * 4 + quad;
        const bf16x8 kf = *(const bf16x8*)(Ks + kr * 256 + (u ^ (kr & 7)) * 8);
        S[nt] = __builtin_amdgcn_mfma_f32_16x16x32_bf16(qf[ks], kf, S[nt], 0, 0, 0);
      }
    }
    __builtin_amdgcn_s_setprio(0);
    u16* Pw = Pb + wave * (16 * 64);
    if (kt == qt) {
      const int qg0 = qt * 64 + wave * 16 + quad * 4;
      const int kg0 = kt * 64 + l16;
#pragma unroll
      for (int nt = 0; nt < 4; ++nt) {
        const int kg = kg0 + nt * 16;
#pragma unroll
        for (int r = 0; r < 4; ++r) {
          float p = exp2f(S[nt][r] * C1 - C2);
          p = (kg <= qg0 + r) ? p : 0.f;
          lacc[r] += p;
          const int qrow = quad * 4 + r;
          const int col = nt * 16 + l16;
          Pw[qrow * 64 + (((col >> 3) ^ (qrow & 7)) * 8) + (col & 7)] = f2bf(p);
        }
      }
    } else {
#pragma unroll
      for (int nt = 0; nt < 4; ++nt) {
#pragma unroll
        for (int r = 0; r < 4; ++r) {
          const float p = exp2f(S[nt][r] * C1 - C2);
          lacc[r] += p;
          const int qrow = quad * 4 + r;
          const int col = nt * 16 + l16;
          Pw[qrow * 64 + (((col >> 3) ^ (qrow & 7)) * 8) + (col & 7)] = f2bf(p);
        }
      }
    }
    __syncthreads();
    if (kt < kt_end) {
#pragma unroll
      for (int p = 0; p < 8; ++p) {
        const int o = p * 4096 + tid * 16;
        const int row = o >> 9;
        const int cg = ((o >> 4) & 31) ^ (row & 7);
        gload16(qkv + kbase + (long)((kt + 1) * 64 + row) * NQKV + cg * 8, (char*)Ks + o);
      }
    }
    bf16x8 pf[2];
#pragma unroll
    for (int ks = 0; ks < 2; ++ks) {
      const int u = ks * 4 + quad;
      pf[ks] = *(const bf16x8*)(Pw + l16 * 64 + (u ^ (l16 & 7)) * 8);
    }
    __builtin_amdgcn_s_setprio(1);
#pragma unroll
    for (int nt = 0; nt < 16; ++nt) {
      const int vr = nt * 16 + l16;
#pragma unroll
      for (int ks = 0; ks < 2; ++ks) {
        const int u = ks * 4 + quad;
        const bf16x8 vf = *(const bf16x8*)(Vs + vr * 64 + (u ^ (vr & 7)) * 8);
        O[nt] = __builtin_amdgcn_mfma_f32_16x16x32_bf16(pf[ks], vf, O[nt], 0, 0, 0);
      }
    }
    __builtin_amdgcn_s_setprio(0);
  }
#pragma unroll
  for (int off = 1; off < 16; off <<= 1)
#pragma unroll
    for (int r = 0; r < 4; ++r) lacc[r] += __shfl_xor(lacc[r], off);

  if (qt < 16) {
    const float rv[4] = {1.0f / lacc[0], 1.0f / lacc[1], 1.0f / lacc[2], 1.0f / lacc[3]};
#pragma unroll
    for (int nt = 0; nt < 16; ++nt) {
      const int col = nt * 16 + l16;
#pragma unroll
      for (int r = 0; r < 4; ++r) {
        const int qrow = wave * 16 + quad * 4 + r;
        ob[((long)(b * SEQ + qt * 64 + qrow)) * EDIM + h * HDIM + col] =
            f2bf(O[nt][r] * rv[r]);
      }
    }
  } else {
    const long pbase = ((long)(bh * 32 + qt) * 2 + kc) * (64 * 256);
#pragma unroll
    for (int nt = 0; nt < 16; ++nt) {
      const int col = nt * 16 + l16;
#pragma unroll
      for (int r = 0; r < 4; ++r) {
        const int qrow = wave * 16 + quad * 4 + r;
        opart[pbase + (long)qrow * 256 + col] = f2bf(O[nt][r]);
      }
    }
    if (l16 == 0) {
      const long lbase = ((long)(bh * 32 + qt) * 2 + kc) * 64;
#pragma unroll
      for (int r = 0; r < 4; ++r)
        lpart[lbase + wave * 16 + quad * 4 + r] = lacc[r];
    }
  }
}

// ---------------- combine split-K partials (qt>=16 only) ----------------
__global__ void __launch_bounds__(256) fa_combine(const u16* __restrict__ opart,
                                                  const float* __restrict__ lpart,
                                                  u16* __restrict__ ob) {
  const int bh = blockIdx.x, qt = 16 + blockIdx.y;
  const int b = bh >> 3, h = bh & 7;
  const long p0 = ((long)(bh * 32 + qt) * 2) * (64 * 256);
  const long l0 = ((long)(bh * 32 + qt) * 2) * 64;
  __shared__ float rl[64];
  if (threadIdx.x < 64) {
    const float l = lpart[l0 + threadIdx.x] + lpart[l0 + 64 + threadIdx.x];
    rl[threadIdx.x] = 1.0f / l;
  }
  __syncthreads();
#pragma unroll
  for (int i = 0; i < 8; ++i) {
    const int e = i * 2048 + threadIdx.x * 8;
    const int row = e >> 8, d = e & 255;
    const u16* a = opart + p0 + e;
    const u16* c = a + 64 * 256;
    float v[8];
#pragma unroll
    for (int j = 0; j < 8; ++j) v[j] = bf2f(a[j]) + bf2f(c[j]);
    const float inv = rl[row];
    u16 o[8];
#pragma unroll
    for (int j = 0; j < 8; ++j) o[j] = f2bf(v[j] * inv);
    *(uint4*)(ob + ((long)(b * SEQ + qt * 64 + row)) * EDIM + h * HDIM + d) =
        *(const uint4*)o;
  }
}

// ---------------- launch ----------------
extern "C" void kernel_launch(void* const* d_in, const int* in_sizes, int n_in,
                              void* d_out, int out_size, void* d_ws, size_t ws_size,
                              hipStream_t stream) {
  const float* x  = (const float*)d_in[0];
  const int* pos  = (const int*)d_in[1];
  const float* Wq = (const float*)d_in[2];
  const float* Wk = (const float*)d_in[3];
  const float* Wv = (const float*)d_in[4];
  const float* Wo = (const float*)d_in[5];
  const float* qw = (const float*)d_in[6];
  const float* kw = (const float*)d_in[7];

  char* ws = (char*)d_ws;
  uint4* xbP   = (uint4*)(ws);               // 16 MiB  x packets [256][4096]  [dead after GEMM1]
  uint4* WcatP = (uint4*)(ws + 16777216L);   // 24 MiB  W packets [256][6144]  [dead after GEMM1]
  u16* Wob  = (u16*)(ws + 41943040L);        //  8 MiB  Wo bf16 (row-major)
  u16* QKVb = (u16*)(ws + 50331648L);        // 48 MiB  qkv bf16 (4096x6144)
  u16* Vt   = (u16*)(ws + 100663296L);       // 16 MiB  V^T bf16 (16x256x2048)
  u16* Ob   = (u16*)(ws + 117440512L);       // 16 MiB  attn out bf16 (4096x2048)
  u16*   Opart = (u16*)(ws);                 // 32 MiB  overlay (dead xbP/WcatP region)
  float* Lpart = (float*)(ws + 33554432L);   // 256 KiB

  cast_pack<<<6144, 256, 0, stream>>>(x, Wq, Wk, Wv, (const float4*)Wo,
                                      xbP, WcatP, (ushort4*)Wob);

  // QKV projection: 2-phase 128^2 on packet layout. grid = (4096/128, 6144/128)
  gemm_pk128<<<dim3(32, 48), 256, 0, stream>>>(xbP, WcatP, QKVb, 4096, 6144, NQKV, DIMM);
  norm_rope_tv<<<18432, 256, 0, stream>>>(QKVb, pos, qw, kw, Vt);
  flash_attn<<<dim3(16, 32, 2), 256, 0, stream>>>(QKVb, Vt, Opart, Lpart, Ob);
  fa_combine<<<dim3(16, 16), 256, 0, stream>>>(Opart, Lpart, Ob);
  gemm_bt<0><<<dim3(32, 16), 256, 0, stream>>>(Ob, Wob, d_out, EDIM, DIMM);
}

// Round 8
// 378.585 us; speedup vs baseline: 1.0975x; 1.0097x over previous
//
#include <hip/hip_runtime.h>
#include <cstdint>
#include <cstddef>

#define SEQ 2048
#define DIMM 2048
#define NHEADS 8
#define HDIM 256
#define BATCH 2
#define NROWS 4096      // BATCH*SEQ
#define EDIM 2048       // NHEADS*HDIM
#define NQKV 6144       // 3*EDIM
#define SCALE 0.0625f   // 1/sqrt(256)
#define LOG2E 1.44269504f

typedef __attribute__((ext_vector_type(8))) short bf16x8;   // 8 bf16 in 4 VGPRs
typedef __attribute__((ext_vector_type(4))) float f32x4;
typedef __attribute__((ext_vector_type(16))) float f32x16;
typedef unsigned short u16;
typedef unsigned int u32;

__device__ __forceinline__ u16 f2bf(float f) {
  union { float f; u32 u; } v; v.f = f;
  u32 r = (v.u + 0x7fffu + ((v.u >> 16) & 1u)) >> 16;   // RNE
  return (u16)r;
}
__device__ __forceinline__ float bf2f(u16 b) {
  union { u32 u; float f; } v; v.u = ((u32)b) << 16;
  return v.f;
}
// async global->LDS, 16B per lane. LDS layout must be lane-linear (wave base + lane*16).
__device__ __forceinline__ void gload16(const void* g, void* l) {
  __builtin_amdgcn_global_load_lds(
      (__attribute__((address_space(1))) void*)(void*)g,
      (__attribute__((address_space(3))) void*)l, 16, 0, 0);
}

// ---------------- cast + k-packet transpose ----------------
// xbP[k/8][m], WcatP[k/8][n], WobP[e/8][d]: 16B packets of 8 bf16 along the K dim.
// Packet layout is HW-verified conflict-free (r5/r6: SQ_LDS_BANK_CONFLICT = 0, passed).
// blocks [0,2048): x tiles; [2048,5120): Wq/Wk/Wv tiles; [5120,6144): Wo tiles.
__global__ void __launch_bounds__(256) cast_pack(const float* __restrict__ x,
                                                 const float* __restrict__ wq,
                                                 const float* __restrict__ wk,
                                                 const float* __restrict__ wv,
                                                 const float* __restrict__ wo,
                                                 uint4* __restrict__ xbp,
                                                 uint4* __restrict__ wcatp,
                                                 uint4* __restrict__ wobp) {
  const int bid = blockIdx.x;
  const int tid = threadIdx.x;
  __shared__ u16 t[64][72];          // 64x64 bf16 tile, row stride 144B (16B-aligned)
  const int kind = (bid < 2048) ? 0 : ((bid < 5120) ? 1 : 2);  // x / Wqkv / Wo
  const int tt = (kind == 0) ? bid : ((kind == 1) ? bid - 2048 : bid - 5120);
  const int r0 = (tt >> 5) << 6;     // output row (m, n, or d) tile base
  const int c0 = (tt & 31) << 6;     // k tile base
  const float* src;
  int srow;
  if (kind == 0)      { src = x;  srow = r0; }
  else if (kind == 2) { src = wo; srow = r0; }
  else {
    const int sel = r0 >> 11;        // 0..2 -> Wq/Wk/Wv
    src = (sel == 0) ? wq : ((sel == 1) ? wk : wv);
    srow = r0 & 2047;
  }
  // read 64x64 fp32 (coalesced rows), cast, store to LDS
#pragma unroll
  for (int i = 0; i < 4; ++i) {
    const int idx = i * 256 + tid;           // 0..1023
    const int r = idx >> 4, c4 = idx & 15;
    const float4 v = *(const float4*)(src + (long)(srow + r) * 2048 + c0 + c4 * 4);
    ushort4 o;
    o.x = f2bf(v.x); o.y = f2bf(v.y); o.z = f2bf(v.z); o.w = f2bf(v.w);
    *(ushort4*)&t[r][c4 * 4] = o;
  }
  __syncthreads();
  // write packets: (c0/8 + u) x (r0 + m); contiguous 1KB/wave
  uint4* dst = (kind == 0) ? xbp : ((kind == 1) ? wcatp : wobp);
  const long R = (kind == 0) ? 4096L : ((kind == 1) ? 6144L : 2048L);
#pragma unroll
  for (int i = 0; i < 2; ++i) {
    const int p = i * 256 + tid;             // 0..511
    const int u = p >> 6, m = p & 63;
    const uint4 pk = *(const uint4*)&t[m][u * 8];
    dst[(long)((c0 >> 3) + u) * R + r0 + m] = pk;
  }
}

// ---------------- GEMM 128x128 2-phase on k-packet layout (QKV projection) -----------
// r6-verified: 0 bank conflicts, MfmaUtil 41.8%, 112.5us full-grid. This round it is
// launched as TWO half-N dispatches (diagnostic: pushes gemm1 below flash/gemm2 in the
// top-5 duration sort so next round's counters attribute the remaining ~95us).
__global__ void __launch_bounds__(256) gemm_pk128(const uint4* __restrict__ AP,
                                                  const uint4* __restrict__ BP,
                                                  u16* __restrict__ Cout,
                                                  int AR, int BR, int N, int K) {
  __shared__ __align__(16) u16 As[8 * 128 * 8];   // 16 KB: packets [u:8][r:128]
  __shared__ __align__(16) u16 Bs[8 * 128 * 8];   // 16 KB
  const int tid = threadIdx.x;
  const int wave = tid >> 6, lane = tid & 63;
  const int l32 = lane & 31, kh = lane >> 5;
  const long bm = (long)blockIdx.x * 128, bn = (long)blockIdx.y * 128;
  const int wm = (wave >> 1) * 64, wn = (wave & 1) * 64;
  f32x16 acc[2][2];
#pragma unroll
  for (int i = 0; i < 2; ++i)
#pragma unroll
    for (int j = 0; j < 2; ++j)
#pragma unroll
      for (int r = 0; r < 16; ++r) acc[i][j][r] = 0.f;

  const int NT = K >> 6;
  for (int t = 0; t < NT; ++t) {
#pragma unroll
    for (int p = 0; p < 4; ++p) {
      const int o = p * 4096 + tid * 16;
      const int u = o >> 11, r = (o >> 4) & 127;
      gload16(AP + (long)(t * 8 + u) * AR + bm + r, (char*)As + o);
      gload16(BP + (long)(t * 8 + u) * BR + bn + r, (char*)Bs + o);
    }
    __syncthreads();
#pragma unroll
    for (int ks = 0; ks < 4; ++ks) {
      bf16x8 af[2], bfr[2];
      const int u = ks * 2 + kh;               // k-packet slot: k = ks*16 + kh*8 + j
#pragma unroll
      for (int t2 = 0; t2 < 2; ++t2) {
        const int ar = wm + t2 * 32 + l32;
        const int br = wn + t2 * 32 + l32;
        af[t2]  = *(const bf16x8*)(As + u * 1024 + ar * 8);   // contiguous, 0-conflict
        bfr[t2] = *(const bf16x8*)(Bs + u * 1024 + br * 8);
      }
#pragma unroll
      for (int i = 0; i < 2; ++i)
#pragma unroll
        for (int j = 0; j < 2; ++j)
          acc[i][j] = __builtin_amdgcn_mfma_f32_32x32x16_bf16(af[i], bfr[j], acc[i][j], 0, 0, 0);
    }
    __syncthreads();
  }
  // epilogue: 32x32 C/D layout col=lane&31, row=(reg&3)+8*(reg>>2)+4*kh
#pragma unroll
  for (int i = 0; i < 2; ++i)
#pragma unroll
    for (int j = 0; j < 2; ++j)
#pragma unroll
      for (int r = 0; r < 16; ++r) {
        const long row = bm + wm + i * 32 + (r & 3) + 8 * (r >> 2) + 4 * kh;
        const long col = bn + wn + j * 32 + l32;
        Cout[row * N + col] = f2bf(acc[i][j][r]);
      }
}

// ---------------- GEMM 128x128 mixed-operand (output projection) ----------------
// A (Ob, row-major) staged with the r4-verified XOR swizzle (conflicted ~4cyc/read);
// B (Wo) in packet layout (0-conflict). Halves gemm2's conflict surcharge without
// touching flash's output path. fp32 out. Unique name -> clean attribution in top-5.
__global__ void __launch_bounds__(256) gemm_mx128(const u16* __restrict__ A,
                                                  const uint4* __restrict__ BP,
                                                  float* __restrict__ Cout,
                                                  int BR, int N, int K) {
  __shared__ __align__(16) u16 As[128 * 64];      // row-major [r:128][k:64]
  __shared__ __align__(16) u16 Bs[8 * 128 * 8];   // packets [u:8][r:128]
  const int tid = threadIdx.x;
  const int wave = tid >> 6, lane = tid & 63;
  const int l32 = lane & 31, kh = lane >> 5;
  const long bm = (long)blockIdx.x * 128, bn = (long)blockIdx.y * 128;
  const int wm = (wave >> 1) * 64, wn = (wave & 1) * 64;
  f32x16 acc[2][2];
#pragma unroll
  for (int i = 0; i < 2; ++i)
#pragma unroll
    for (int j = 0; j < 2; ++j)
#pragma unroll
      for (int r = 0; r < 16; ++r) acc[i][j][r] = 0.f;

  const int NT = K >> 6;
  for (int t = 0; t < NT; ++t) {
    const int k0 = t * 64;
#pragma unroll
    for (int p = 0; p < 4; ++p) {
      const int o = p * 4096 + tid * 16;
      // A: row-major swizzled stage (gemm_bt pattern, r4-verified)
      const int row = o >> 7;
      const int cg = ((o >> 4) & 7) ^ (row & 7);
      gload16(A + (bm + row) * (long)K + k0 + cg * 8, (char*)As + o);
      // B: packet stage (gemm_pk128 pattern, r6-verified)
      const int u = o >> 11, r = (o >> 4) & 127;
      gload16(BP + (long)(t * 8 + u) * BR + bn + r, (char*)Bs + o);
    }
    __syncthreads();
#pragma unroll
    for (int ks = 0; ks < 4; ++ks) {
      bf16x8 af[2], bfr[2];
      const int u = ks * 2 + kh;
#pragma unroll
      for (int t2 = 0; t2 < 2; ++t2) {
        const int ar = wm + t2 * 32 + l32;
        const int br = wn + t2 * 32 + l32;
        af[t2]  = *(const bf16x8*)(As + ar * 64 + ((u ^ (ar & 7)) * 8));  // swizzled
        bfr[t2] = *(const bf16x8*)(Bs + u * 1024 + br * 8);               // packet
      }
#pragma unroll
      for (int i = 0; i < 2; ++i)
#pragma unroll
        for (int j = 0; j < 2; ++j)
          acc[i][j] = __builtin_amdgcn_mfma_f32_32x32x16_bf16(af[i], bfr[j], acc[i][j], 0, 0, 0);
    }
    __syncthreads();
  }
#pragma unroll
  for (int i = 0; i < 2; ++i)
#pragma unroll
    for (int j = 0; j < 2; ++j)
#pragma unroll
      for (int r = 0; r < 16; ++r) {
        const long row = bm + wm + i * 32 + (r & 3) + 8 * (r >> 2) + 4 * kh;
        const long col = bn + wn + j * 32 + l32;
        Cout[row * N + col] = acc[i][j][r];
      }
}

// ---------------- fused RMSnorm+RoPE (q/k) + V transpose, one launch ----------------
__global__ void __launch_bounds__(256) norm_rope_tv(u16* __restrict__ qkv,
                                                    const int* __restrict__ pos_ids,
                                                    const float* __restrict__ qw,
                                                    const float* __restrict__ kw,
                                                    u16* __restrict__ vt) {
  __shared__ u16 tile[64][73];
  if (blockIdx.x < 16384) {
    const int job = blockIdx.x * 4 + (threadIdx.x >> 6);
    const int lane = threadIdx.x & 63;
    const int which = job >> 15;       // 0 = q, 1 = k
    const int j2 = job & 32767;
    const int r = j2 >> 3;             // row 0..4095 (b*S+s)
    const int h = j2 & 7;
    const int s = r & (SEQ - 1);
    const int pos = pos_ids[s];
    const float* w = which ? kw : qw;
    u16* p = qkv + (long)r * NQKV + which * EDIM + h * HDIM;

    float x0 = bf2f(p[lane]);
    float x1 = bf2f(p[lane + 64]);
    float x2 = bf2f(p[lane + 128]);
    float x3 = bf2f(p[lane + 192]);
    float ss = x0 * x0 + x1 * x1 + x2 * x2 + x3 * x3;
#pragma unroll
    for (int off = 1; off < 64; off <<= 1) ss += __shfl_xor(ss, off);
    const float rinv = rsqrtf(ss * (1.0f / HDIM) + 1e-6f);
    x0 *= rinv * w[lane];       x1 *= rinv * w[lane + 64];
    x2 *= rinv * w[lane + 128]; x3 *= rinv * w[lane + 192];
    const float L2TEN4 = 13.287712379549449f;  // log2(10000)
    const float f0 = exp2f(-(2.0f * lane / HDIM) * L2TEN4);
    const float f1 = exp2f(-(2.0f * (lane + 64) / HDIM) * L2TEN4);
    const float a0 = pos * f0, a1 = pos * f1;
    float s0, c0, s1, c1;
    __sincosf(a0, &s0, &c0);
    __sincosf(a1, &s1, &c1);
    p[lane]       = f2bf(x0 * c0 - x2 * s0);
    p[lane + 64]  = f2bf(x1 * c1 - x3 * s1);
    p[lane + 128] = f2bf(x2 * c0 + x0 * s0);
    p[lane + 192] = f2bf(x3 * c1 + x1 * s1);
  } else {
    const int t = blockIdx.x - 16384;
    const int tid = threadIdx.x;
    const int st = (t & 31) * 64;
    const int dt = ((t >> 5) & 3) * 64;
    const int bh = t >> 7;
    const int b = bh >> 3, h = bh & 7;
    const u16* src = qkv + (long)(b * SEQ + st) * NQKV + 2 * EDIM + h * HDIM + dt;
#pragma unroll
    for (int p = 0; p < 2; ++p) {
      const int idx = p * 2048 + tid * 8;
      const int sr = idx >> 6, dc = idx & 63;
      const uint4 v = *(const uint4*)(src + (long)sr * NQKV + dc);
      const u16* pv = (const u16*)&v;
#pragma unroll
      for (int e = 0; e < 8; ++e) tile[sr][dc + e] = pv[e];
    }
    __syncthreads();
    u16* dst = vt + ((long)bh * HDIM + dt) * SEQ + st;
#pragma unroll
    for (int p = 0; p < 2; ++p) {
      const int idx = p * 2048 + tid * 8;
      const int dr = idx >> 6, sc = idx & 63;
      u16 tmp[8];
#pragma unroll
      for (int e = 0; e < 8; ++e) tmp[e] = tile[sc + e][dr];
      *(uint4*)(dst + (long)dr * SEQ + sc) = *(const uint4*)tmp;
    }
  }
}

// ---------------- flash attention v3 (r4/r6 config): 2-barrier loop + T5 setprio -----
__global__ void __launch_bounds__(256) flash_attn(const u16* __restrict__ qkv,
                                                  const u16* __restrict__ vt,
                                                  u16* __restrict__ opart,
                                                  float* __restrict__ lpart,
                                                  u16* __restrict__ ob) {
  const int bh = blockIdx.x, b = bh >> 3, h = bh & 7;
  const int qt = 31 - (int)blockIdx.y;
  const int kc = blockIdx.z;
  if (kc && qt < 16) return;
  const int kt0 = kc * 16;
  const int kt_end = (qt < kt0 + 15) ? qt : (kt0 + 15);

  __shared__ __align__(16) u16 Ks[64 * 256];
  __shared__ __align__(16) u16 Vs[256 * 64];
  __shared__ __align__(16) u16 Pb[4 * 16 * 64];
  const int tid = threadIdx.x;
  const int wave = tid >> 6, lane = tid & 63;
  const int quad = lane >> 4, l16 = lane & 15;
  const long qbase = (long)(b * SEQ + qt * 64) * NQKV + h * HDIM;
  const long kbase = (long)(b * SEQ) * NQKV + EDIM + h * HDIM;
  const long vbase = (long)bh * HDIM * SEQ;

#pragma unroll
  for (int p = 0; p < 8; ++p) {
    const int o = p * 4096 + tid * 16;
    const int row = o >> 9;
    const int cg = ((o >> 4) & 31) ^ (row & 7);
    gload16(qkv + qbase + (long)row * NQKV + cg * 8, (char*)Ks + o);
  }
  __syncthreads();
  bf16x8 qf[8];
  {
    const int qr = wave * 16 + l16;
#pragma unroll
    for (int ks = 0; ks < 8; ++ks) {
      const int u = ks * 4 + quad;
      qf[ks] = *(const bf16x8*)(Ks + qr * 256 + (u ^ (qr & 7)) * 8);
    }
  }
  __syncthreads();

#pragma unroll
  for (int p = 0; p < 8; ++p) {
    const int o = p * 4096 + tid * 16;
    const int row = o >> 9;
    const int cg = ((o >> 4) & 31) ^ (row & 7);
    gload16(qkv + kbase + (long)(kt0 * 64 + row) * NQKV + cg * 8, (char*)Ks + o);
  }

  const f32x4 fz = {0.f, 0.f, 0.f, 0.f};
  f32x4 O[16];
#pragma unroll
  for (int t = 0; t < 16; ++t) O[t] = fz;
  float lacc[4] = {0.f, 0.f, 0.f, 0.f};
  const float C1 = SCALE * LOG2E;
  const float C2 = 16.0f * LOG2E;

  for (int kt = kt0; kt <= kt_end; ++kt) {
    __syncthreads();
#pragma unroll
    for (int p = 0; p < 8; ++p) {
      const int o = p * 4096 + tid * 16;
      const int row = o >> 7;
      const int cg = ((o >> 4) & 7) ^ (row & 7);
      gload16(vt + vbase + (long)row * SEQ + kt * 64 + cg * 8, (char*)Vs + o);
    }
    f32x4 S[4];
#pragma unroll
    for (int nt = 0; nt < 4; ++nt) S[nt] = fz;
    __builtin_amdgcn_s_setprio(1);
#pragma unroll
    for (int nt = 0; nt < 4; ++nt) {
      const int kr = nt * 16 + l16;
#pragma unroll
      for (int ks = 0; ks < 8; ++ks) {
        const int u = ks * 4 + quad;
        const bf16x8 kf = *(const bf16x8*)(Ks + kr * 256 + (u ^ (kr & 7)) * 8);
        S[nt] = __builtin_amdgcn_mfma_f32_16x16x32_bf16(qf[ks], kf, S[nt], 0, 0, 0);
      }
    }
    __builtin_amdgcn_s_setprio(0);
    u16* Pw = Pb + wave * (16 * 64);
    if (kt == qt) {
      const int qg0 = qt * 64 + wave * 16 + quad * 4;
      const int kg0 = kt * 64 + l16;
#pragma unroll
      for (int nt = 0; nt < 4; ++nt) {
        const int kg = kg0 + nt * 16;
#pragma unroll
        for (int r = 0; r < 4; ++r) {
          float p = exp2f(S[nt][r] * C1 - C2);
          p = (kg <= qg0 + r) ? p : 0.f;
          lacc[r] += p;
          const int qrow = quad * 4 + r;
          const int col = nt * 16 + l16;
          Pw[qrow * 64 + (((col >> 3) ^ (qrow & 7)) * 8) + (col & 7)] = f2bf(p);
        }
      }
    } else {
#pragma unroll
      for (int nt = 0; nt < 4; ++nt) {
#pragma unroll
        for (int r = 0; r < 4; ++r) {
          const float p = exp2f(S[nt][r] * C1 - C2);
          lacc[r] += p;
          const int qrow = quad * 4 + r;
          const int col = nt * 16 + l16;
          Pw[qrow * 64 + (((col >> 3) ^ (qrow & 7)) * 8) + (col & 7)] = f2bf(p);
        }
      }
    }
    __syncthreads();
    if (kt < kt_end) {
#pragma unroll
      for (int p = 0; p < 8; ++p) {
        const int o = p * 4096 + tid * 16;
        const int row = o >> 9;
        const int cg = ((o >> 4) & 31) ^ (row & 7);
        gload16(qkv + kbase + (long)((kt + 1) * 64 + row) * NQKV + cg * 8, (char*)Ks + o);
      }
    }
    bf16x8 pf[2];
#pragma unroll
    for (int ks = 0; ks < 2; ++ks) {
      const int u = ks * 4 + quad;
      pf[ks] = *(const bf16x8*)(Pw + l16 * 64 + (u ^ (l16 & 7)) * 8);
    }
    __builtin_amdgcn_s_setprio(1);
#pragma unroll
    for (int nt = 0; nt < 16; ++nt) {
      const int vr = nt * 16 + l16;
#pragma unroll
      for (int ks = 0; ks < 2; ++ks) {
        const int u = ks * 4 + quad;
        const bf16x8 vf = *(const bf16x8*)(Vs + vr * 64 + (u ^ (vr & 7)) * 8);
        O[nt] = __builtin_amdgcn_mfma_f32_16x16x32_bf16(pf[ks], vf, O[nt], 0, 0, 0);
      }
    }
    __builtin_amdgcn_s_setprio(0);
  }
#pragma unroll
  for (int off = 1; off < 16; off <<= 1)
#pragma unroll
    for (int r = 0; r < 4; ++r) lacc[r] += __shfl_xor(lacc[r], off);

  if (qt < 16) {
    const float rv[4] = {1.0f / lacc[0], 1.0f / lacc[1], 1.0f / lacc[2], 1.0f / lacc[3]};
#pragma unroll
    for (int nt = 0; nt < 16; ++nt) {
      const int col = nt * 16 + l16;
#pragma unroll
      for (int r = 0; r < 4; ++r) {
        const int qrow = wave * 16 + quad * 4 + r;
        ob[((long)(b * SEQ + qt * 64 + qrow)) * EDIM + h * HDIM + col] =
            f2bf(O[nt][r] * rv[r]);
      }
    }
  } else {
    const long pbase = ((long)(bh * 32 + qt) * 2 + kc) * (64 * 256);
#pragma unroll
    for (int nt = 0; nt < 16; ++nt) {
      const int col = nt * 16 + l16;
#pragma unroll
      for (int r = 0; r < 4; ++r) {
        const int qrow = wave * 16 + quad * 4 + r;
        opart[pbase + (long)qrow * 256 + col] = f2bf(O[nt][r]);
      }
    }
    if (l16 == 0) {
      const long lbase = ((long)(bh * 32 + qt) * 2 + kc) * 64;
#pragma unroll
      for (int r = 0; r < 4; ++r)
        lpart[lbase + wave * 16 + quad * 4 + r] = lacc[r];
    }
  }
}

// ---------------- combine split-K partials (qt>=16 only) ----------------
__global__ void __launch_bounds__(256) fa_combine(const u16* __restrict__ opart,
                                                  const float* __restrict__ lpart,
                                                  u16* __restrict__ ob) {
  const int bh = blockIdx.x, qt = 16 + blockIdx.y;
  const int b = bh >> 3, h = bh & 7;
  const long p0 = ((long)(bh * 32 + qt) * 2) * (64 * 256);
  const long l0 = ((long)(bh * 32 + qt) * 2) * 64;
  __shared__ float rl[64];
  if (threadIdx.x < 64) {
    const float l = lpart[l0 + threadIdx.x] + lpart[l0 + 64 + threadIdx.x];
    rl[threadIdx.x] = 1.0f / l;
  }
  __syncthreads();
#pragma unroll
  for (int i = 0; i < 8; ++i) {
    const int e = i * 2048 + threadIdx.x * 8;
    const int row = e >> 8, d = e & 255;
    const u16* a = opart + p0 + e;
    const u16* c = a + 64 * 256;
    float v[8];
#pragma unroll
    for (int j = 0; j < 8; ++j) v[j] = bf2f(a[j]) + bf2f(c[j]);
    const float inv = rl[row];
    u16 o[8];
#pragma unroll
    for (int j = 0; j < 8; ++j) o[j] = f2bf(v[j] * inv);
    *(uint4*)(ob + ((long)(b * SEQ + qt * 64 + row)) * EDIM + h * HDIM + d) =
        *(const uint4*)o;
  }
}

// ---------------- launch ----------------
extern "C" void kernel_launch(void* const* d_in, const int* in_sizes, int n_in,
                              void* d_out, int out_size, void* d_ws, size_t ws_size,
                              hipStream_t stream) {
  const float* x  = (const float*)d_in[0];
  const int* pos  = (const int*)d_in[1];
  const float* Wq = (const float*)d_in[2];
  const float* Wk = (const float*)d_in[3];
  const float* Wv = (const float*)d_in[4];
  const float* Wo = (const float*)d_in[5];
  const float* qw = (const float*)d_in[6];
  const float* kw = (const float*)d_in[7];

  char* ws = (char*)d_ws;
  uint4* xbP   = (uint4*)(ws);               // 16 MiB  x packets [256][4096]  [dead after GEMM1]
  uint4* WcatP = (uint4*)(ws + 16777216L);   // 24 MiB  W packets [256][6144]  [dead after GEMM1]
  uint4* WobP  = (uint4*)(ws + 41943040L);   //  8 MiB  Wo packets [256][2048]
  u16* QKVb = (u16*)(ws + 50331648L);        // 48 MiB  qkv bf16 (4096x6144)
  u16* Vt   = (u16*)(ws + 100663296L);       // 16 MiB  V^T bf16 (16x256x2048)
  u16* Ob   = (u16*)(ws + 117440512L);       // 16 MiB  attn out bf16 (4096x2048)
  u16*   Opart = (u16*)(ws);                 // 32 MiB  overlay (dead xbP/WcatP region)
  float* Lpart = (float*)(ws + 33554432L);   // 256 KiB

  cast_pack<<<6144, 256, 0, stream>>>(x, Wq, Wk, Wv, Wo, xbP, WcatP, WobP);

  // QKV projection split into two half-N dispatches (diagnostic: exposes flash/gemm2
  // in next round's top-5). Half 2 offsets B packets and C columns by +3072.
  gemm_pk128<<<dim3(32, 24), 256, 0, stream>>>(xbP, WcatP, QKVb, 4096, 6144, NQKV, DIMM);
  gemm_pk128<<<dim3(32, 24), 256, 0, stream>>>(xbP, WcatP + 3072, QKVb + 3072,
                                               4096, 6144, NQKV, DIMM);
  norm_rope_tv<<<18432, 256, 0, stream>>>(QKVb, pos, qw, kw, Vt);
  flash_attn<<<dim3(16, 32, 2), 256, 0, stream>>>(QKVb, Vt, Opart, Lpart, Ob);
  fa_combine<<<dim3(16, 16), 256, 0, stream>>>(Opart, Lpart, Ob);
  // output projection: mixed-operand kernel (A row-major swizzled, B packets), fp32 out
  gemm_mx128<<<dim3(32, 16), 256, 0, stream>>>(Ob, WobP, (float*)d_out, 2048, DIMM, EDIM);
}